// Round 7
// baseline (81.295 us; speedup 1.0000x reference)
//
#include <hip/hip_runtime.h>
#include <hip/hip_cooperative_groups.h>
#include <math.h>
#include <utility>

namespace cg = cooperative_groups;

#define NB 16
#define NS 2048
#define NE 8
#define NH 2
#define NF 512
#define DEG 6
#define NMONO 210          // #monomials in 4 vars, total degree <= 6
#define KPB 64             // keys per phase-A task
#define NCHUNK 32          // key chunks per (b,h)
#define PHI_LD 66          // fp16 row stride (64 keys + 2 pad)
#define QPB 128
#define LNEPS 1e-5f
#define PART_STRIDE (5 * NMONO)

typedef float f32x2 __attribute__((ext_vector_type(2)));
typedef _Float16 h2 __attribute__((ext_vector_type(2)));

#if defined(__has_builtin)
# if __has_builtin(__builtin_amdgcn_fdot2)
#  define FDOT2(a,b,c) __builtin_amdgcn_fdot2((a),(b),(c),false)
# endif
#endif
#ifndef FDOT2
static __device__ __forceinline__ float fdot2_sw(h2 a, h2 b, float c) {
    return c + (float)a.x * (float)b.x + (float)a.y * (float)b.y;
}
# define FDOT2(a,b,c) fdot2_sw((a),(b),(c))
#endif

// Degree-6 truncated Chebyshev approx of e^x on [-2,2] in t=x/2 (power basis).
constexpr float ACOEF_C[7] = {0.99994459f, 2.00308514f, 2.00174650f,
                              1.30890404f, 0.65803033f, 0.31441604f, 0.10241921f};

constexpr int mono_e(int idx) {
    int i = 0;
    for (int e0 = 0; e0 <= DEG; ++e0)
        for (int e1 = 0; e1 <= DEG - e0; ++e1)
            for (int e2 = 0; e2 <= DEG - e0 - e1; ++e2)
                for (int e3 = 0; e3 <= DEG - e0 - e1 - e2; ++e3) {
                    if (i == idx) return (e0 << 12) | (e1 << 8) | (e2 << 4) | e3;
                    ++i;
                }
    return 0;
}
constexpr float mfact(int n) { float r = 1.f; for (int i = 2; i <= n; ++i) r *= (float)i; return r; }
constexpr float mono_c(int idx) {
    const int E = mono_e(idx);
    const int e0 = E >> 12, e1 = (E >> 8) & 15, e2 = (E >> 4) & 15, e3 = E & 15;
    const int d = e0 + e1 + e2 + e3;
    return ACOEF_C[d] * (mfact(d) / (mfact(e0) * mfact(e1) * mfact(e2) * mfact(e3)));
}

template <int BEG, class F, int... Is>
__device__ __forceinline__ void sf_impl(F f, std::integer_sequence<int, Is...>) {
    (f(std::integral_constant<int, BEG + Is>{}), ...);
}
template <int BEG, int END, class F>
__device__ __forceinline__ void static_for(F f) {
    sf_impl<BEG>(f, std::make_integer_sequence<int, END - BEG>{});
}

template <int BEG, int END>
__device__ __forceinline__ void phi_body(_Float16* __restrict__ Phi, int lane,
                                         const float (&pw0)[7], const float (&pw1)[7],
                                         const float (&pw2)[7], const float (&pw3)[7]) {
    static_for<BEG, END>([&](auto Ic) {
        constexpr int idx = Ic.value;
        constexpr int E = mono_e(idx);
        constexpr float C = mono_c(idx);
        const float v = C * (pw0[E >> 12] * pw1[(E >> 8) & 15]) *
                            (pw2[(E >> 4) & 15] * pw3[E & 15]);
        Phi[idx * PHI_LD + lane] = (_Float16)v;
    });
}

template <int BEG, int END>
__device__ __forceinline__ void p2_body2(const float4* __restrict__ Mn,
                                         const float* __restrict__ Md, int base,
                                         const float (&pwA)[4][7], const float (&pwB)[4][7],
                                         f32x2& a01A, f32x2& a23A, float& adA,
                                         f32x2& a01B, f32x2& a23B, float& adB) {
    static_for<BEG, END>([&](auto Ic) {
        constexpr int idx = Ic.value;
        constexpr int E = mono_e(idx);
        constexpr int e0 = E >> 12, e1 = (E >> 8) & 15, e2 = (E >> 4) & 15, e3 = E & 15;
        const float4 mv = Mn[base + idx];     // wave-uniform broadcast
        const float  md = Md[base + idx];
        const f32x2 m01 = {mv.x, mv.y}, m23 = {mv.z, mv.w};
        const float PA = (pwA[0][e0] * pwA[1][e1]) * (pwA[2][e2] * pwA[3][e3]);
        const float PB = (pwB[0][e0] * pwB[1][e1]) * (pwB[2][e2] * pwB[3][e3]);
        a01A += PA * m01;  a23A += PA * m23;  adA += PA * md;
        a01B += PB * m01;  a23B += PB * m23;  adB += PB * md;
    });
}

struct PhaseA_sm {
    _Float16 Phi[4][NMONO * PHI_LD];   // 110880 B (offset of kvh is 16B-aligned)
    _Float16 kvh[4][KPB / 2][8];       // 2048 B
};
struct PhaseB_sm {
    float4 Mn[2 * NMONO];
    float  Md[2 * NMONO];
    float  z[NE][QPB];
    float  x1[NE][QPB];
    float  zf[NE][QPB];
    float  attn[NE][QPB];
    float  part_a[4][256][5];
    float  part_f[8][QPB][9];
};
union USm { PhaseA_sm a; PhaseB_sm b; };

__global__ __launch_bounds__(1024)
void fused_qtb(const float* __restrict__ x, const float* __restrict__ theta_rx,
               const float* __restrict__ w_out, const float* __restrict__ theta_ry,
               const float* __restrict__ w1, const float* __restrict__ b1,
               const float* __restrict__ w2, const float* __restrict__ b2,
               const float* __restrict__ g1, const float* __restrict__ be1,
               const float* __restrict__ g2, const float* __restrict__ be2,
               float* __restrict__ ws, float* __restrict__ out) {
    __shared__ USm sm;                         // 110.3 KB union
    __shared__ float w1_s[NF][NE];             // persistent (staged during phase A)
    __shared__ float w2t_s[NF][NE];
    __shared__ float b1_s[NF];
    __shared__ float wout_s[NE][NE];
    __shared__ float th_s[8], cry_s[8], g1_s[8], be1_s[8], g2_s[8], be2_s[8], b2_s[8];

    const int t = threadIdx.x, bid = blockIdx.x;

    // ---- stage weights + consts (overlaps phase A compute below) ----
    for (int i = t; i < NF * NE; i += 1024) {
        ((float*)w1_s)[i] = w1[i];
        const int e = i >> 9, f = i & (NF - 1);
        w2t_s[f][e] = w2[i];
    }
    if (t < NF) b1_s[t] = b1[t];
    if (t < NE * NE) ((float*)wout_s)[t] = w_out[t];
    if (t < 8) {
        th_s[t]  = theta_rx[t];
        cry_s[t] = __cosf(theta_ry[t]);
        g1_s[t]  = g1[t];  be1_s[t] = be1[t];
        g2_s[t]  = g2[t];  be2_s[t] = be2[t];
        b2_s[t]  = b2[t];
    }
    __syncthreads();

    // ================= phase A: moments (4 key-chunk tasks per block) ======
    {
        const int g = t >> 8, tt = t & 255;
        const int tk = bid * 4 + g;            // old k1 blockIdx
        const int kc = tk & 31, h = (tk >> 5) & 1, bb = tk >> 6;
        const int lane = tt & 63, wq = tt >> 6;

        const float* xr = x + ((size_t)bb * NS + kc * KPB + lane) * NE;
        const float4 v0 = *reinterpret_cast<const float4*>(xr);
        const float4 v1 = *reinterpret_cast<const float4*>(xr + 4);
        const float c0 = __cosf(v0.x + th_s[0]), c1 = __cosf(v0.y + th_s[1]);
        const float c2 = __cosf(v0.z + th_s[2]), c3 = __cosf(v0.w + th_s[3]);
        const float c4 = __cosf(v1.x + th_s[4]), c5 = __cosf(v1.y + th_s[5]);
        const float c6 = __cosf(v1.z + th_s[6]), c7 = __cosf(v1.w + th_s[7]);
        const float p1 = c0*c1, p2 = p1*c2, p3 = p2*c3, p4 = p3*c4;
        const float p5 = p4*c5, p6 = p5*c6, p7 = p6*c7;
        float k0, k1v, k2v, k3v;
        if (h == 0) {
            const float s6 = c7*c6, s5 = s6*c5, s4 = s5*c4, s3 = s4*c3, s2 = s3*c2;
            k0 = s2*c1; k1v = p1; k2v = p2; k3v = p3;
        } else {
            k0 = p4; k1v = p5; k2v = p6; k3v = p7;
        }
        if (tt < 64) {
            const int j = tt >> 1, par = tt & 1;
            sm.a.kvh[g][j][0 + par] = (_Float16)k0;  sm.a.kvh[g][j][2 + par] = (_Float16)k1v;
            sm.a.kvh[g][j][4 + par] = (_Float16)k2v; sm.a.kvh[g][j][6 + par] = (_Float16)k3v;
        }
        float pw0[7], pw1[7], pw2[7], pw3[7];
        pw0[0] = pw1[0] = pw2[0] = pw3[0] = 1.f;
        #pragma unroll
        for (int i = 1; i <= DEG; ++i) {
            pw0[i] = pw0[i-1] * k0;  pw1[i] = pw1[i-1] * k1v;
            pw2[i] = pw2[i-1] * k2v; pw3[i] = pw3[i-1] * k3v;
        }
        _Float16* PhiG = &sm.a.Phi[g][0];
        switch (wq) {
            case 0: phi_body<0,   53 >(PhiG, lane, pw0, pw1, pw2, pw3); break;
            case 1: phi_body<53,  106>(PhiG, lane, pw0, pw1, pw2, pw3); break;
            case 2: phi_body<106, 159>(PhiG, lane, pw0, pw1, pw2, pw3); break;
            default: phi_body<159, 210>(PhiG, lane, pw0, pw1, pw2, pw3); break;
        }
    }
    __syncthreads();

    {   // feature-GEMM per group
        const int g = t >> 8, tt = t & 255;
        const int tk = bid * 4 + g;
        if (tt < NMONO) {
            const h2 one2 = {(_Float16)1.f, (_Float16)1.f};
            const _Float16* PhiG = &sm.a.Phi[g][0];
            float a0 = 0.f, a1 = 0.f, a2 = 0.f, a3 = 0.f, a4 = 0.f;
            #pragma unroll 8
            for (int j = 0; j < KPB / 2; ++j) {
                const h2 phi2 = *reinterpret_cast<const h2*>(&PhiG[tt * PHI_LD + 2 * j]);
                const float4 kv4 = *reinterpret_cast<const float4*>(&sm.a.kvh[g][j][0]);
                const h2 kA = __builtin_bit_cast(h2, kv4.x);
                const h2 kB = __builtin_bit_cast(h2, kv4.y);
                const h2 kC = __builtin_bit_cast(h2, kv4.z);
                const h2 kD = __builtin_bit_cast(h2, kv4.w);
                a0 = FDOT2(phi2, kA, a0);
                a1 = FDOT2(phi2, kB, a1);
                a2 = FDOT2(phi2, kC, a2);
                a3 = FDOT2(phi2, kD, a3);
                a4 = FDOT2(phi2, one2, a4);
            }
            float* dst = ws + (size_t)tk * PART_STRIDE;
            dst[0 * NMONO + tt] = a0;
            dst[1 * NMONO + tt] = a1;
            dst[2 * NMONO + tt] = a2;
            dst[3 * NMONO + tt] = a3;
            dst[4 * NMONO + tt] = a4;
        }
    }

    cg::this_grid().sync();

    // ================= phase B: queries + fused epilogue ====================
    const int b = bid >> 4, qc = bid & 15;

    if (t < 2 * NMONO) {   // reduce PART (32 chunks) -> moments in LDS
        const int h = (t >= NMONO) ? 1 : 0;
        const int a = t - h * NMONO;
        const float* src = ws + (size_t)((b * 2 + h) * NCHUNK) * PART_STRIDE;
        float s0 = 0.f, s1 = 0.f, s2 = 0.f, s3 = 0.f, s4 = 0.f;
        #pragma unroll 4
        for (int kc = 0; kc < NCHUNK; ++kc) {
            const float* p = src + (size_t)kc * PART_STRIDE;
            s0 += p[0 * NMONO + a]; s1 += p[1 * NMONO + a];
            s2 += p[2 * NMONO + a]; s3 += p[3 * NMONO + a];
            s4 += p[4 * NMONO + a];
        }
        sm.b.Mn[t] = make_float4(s0, s1, s2, s3);
        sm.b.Md[t] = s4;
    }
    __syncthreads();

    // ---- P1: z for the 128 query rows ----
    if (t < QPB) {
        const float* xr = x + ((size_t)b * NS + qc * QPB + t) * NE;
        const float4 v0 = *reinterpret_cast<const float4*>(xr);
        const float4 v1 = *reinterpret_cast<const float4*>(xr + 4);
        const float c0 = __cosf(v0.x + th_s[0]), c1 = __cosf(v0.y + th_s[1]);
        const float c2 = __cosf(v0.z + th_s[2]), c3 = __cosf(v0.w + th_s[3]);
        const float c4 = __cosf(v1.x + th_s[4]), c5 = __cosf(v1.y + th_s[5]);
        const float c6 = __cosf(v1.z + th_s[6]), c7 = __cosf(v1.w + th_s[7]);
        const float p1 = c0*c1, p2 = p1*c2, p3 = p2*c3, p4 = p3*c4;
        const float p5 = p4*c5, p6 = p5*c6, p7 = p6*c7;
        const float s6 = c7*c6, s5 = s6*c5, s4 = s5*c4, s3 = s4*c3, s2 = s3*c2;
        sm.b.z[0][t] = s2*c1; sm.b.z[1][t] = p1; sm.b.z[2][t] = p2; sm.b.z[3][t] = p3;
        sm.b.z[4][t] = p4;    sm.b.z[5][t] = p5; sm.b.z[6][t] = p6; sm.b.z[7][t] = p7;
    }
    __syncthreads();

    // ---- P2: 8 waves, wave = (g,h), 2 rows per lane ----
    if (t < 512) {
        const int w = t >> 6, l = t & 63;
        const int g = w >> 1, h = w & 1;
        const int rA = l, rB = l + 64;
        float pwA[4][7], pwB[4][7];
        #pragma unroll
        for (int d = 0; d < 4; ++d) {
            const float uA = sm.b.z[h*4+d][rA] * 0.25f;
            const float uB = sm.b.z[h*4+d][rB] * 0.25f;
            pwA[d][0] = 1.f; pwB[d][0] = 1.f;
            #pragma unroll
            for (int i = 1; i <= DEG; ++i) {
                pwA[d][i] = pwA[d][i-1] * uA;
                pwB[d][i] = pwB[d][i-1] * uB;
            }
        }
        f32x2 a01A = {0.f,0.f}, a23A = {0.f,0.f}, a01B = {0.f,0.f}, a23B = {0.f,0.f};
        float adA = 0.f, adB = 0.f;
        const int base = h * NMONO;
        switch (g) {
            case 0: p2_body2<0,   53 >(sm.b.Mn, sm.b.Md, base, pwA, pwB, a01A, a23A, adA, a01B, a23B, adB); break;
            case 1: p2_body2<53,  106>(sm.b.Mn, sm.b.Md, base, pwA, pwB, a01A, a23A, adA, a01B, a23B, adB); break;
            case 2: p2_body2<106, 159>(sm.b.Mn, sm.b.Md, base, pwA, pwB, a01A, a23A, adA, a01B, a23B, adB); break;
            default: p2_body2<159, 210>(sm.b.Mn, sm.b.Md, base, pwA, pwB, a01A, a23A, adA, a01B, a23B, adB); break;
        }
        float* pa = &sm.b.part_a[g][h * 128 + rA][0];
        pa[0] = a01A.x; pa[1] = a01A.y; pa[2] = a23A.x; pa[3] = a23A.y; pa[4] = adA;
        float* pb = &sm.b.part_a[g][h * 128 + rB][0];
        pb[0] = a01B.x; pb[1] = a01B.y; pb[2] = a23B.x; pb[3] = a23B.y; pb[4] = adB;
    }
    __syncthreads();

    // ---- P3: combine groups, normalize ----
    if (t < 256) {
        const int h = t >> 7, r = t & 127;
        float n0 = 0.f, n1 = 0.f, n2 = 0.f, n3 = 0.f, dd = 0.f;
        #pragma unroll
        for (int g = 0; g < 4; ++g) {
            const float* pa = &sm.b.part_a[g][t][0];
            n0 += pa[0]; n1 += pa[1]; n2 += pa[2]; n3 += pa[3]; dd += pa[4];
        }
        const float inv = 1.0f / dd;
        sm.b.attn[h*4+0][r] = n0 * inv; sm.b.attn[h*4+1][r] = n1 * inv;
        sm.b.attn[h*4+2][r] = n2 * inv; sm.b.attn[h*4+3][r] = n3 * inv;
    }
    __syncthreads();

    // ---- P4: out_proj -> LN1 -> zf ----
    if (t < QPB) {
        float av[NE];
        #pragma unroll
        for (int e = 0; e < NE; ++e) av[e] = sm.b.attn[e][t];
        float y[NE];
        #pragma unroll
        for (int e = 0; e < NE; ++e) {
            float acc = 0.f;
            #pragma unroll
            for (int k = 0; k < NE; ++k) acc += av[k] * wout_s[e][k];
            y[e] = acc;
        }
        const float* xr = x + ((size_t)b * NS + qc * QPB + t) * NE;
        const float4 xv0 = *reinterpret_cast<const float4*>(xr);
        const float4 xv1 = *reinterpret_cast<const float4*>(xr + 4);
        float t1[NE];
        t1[0] = xv0.x + y[0]; t1[1] = xv0.y + y[1]; t1[2] = xv0.z + y[2]; t1[3] = xv0.w + y[3];
        t1[4] = xv1.x + y[4]; t1[5] = xv1.y + y[5]; t1[6] = xv1.z + y[6]; t1[7] = xv1.w + y[7];
        float mu = 0.f;
        #pragma unroll
        for (int e = 0; e < NE; ++e) mu += t1[e];
        mu *= 0.125f;
        float var = 0.f;
        #pragma unroll
        for (int e = 0; e < NE; ++e) { const float d = t1[e] - mu; var += d * d; }
        var *= 0.125f;
        const float inv1 = rsqrtf(var + LNEPS);
        #pragma unroll
        for (int e = 0; e < NE; ++e) {
            const float x1e = (t1[e] - mu) * inv1 * g1_s[e] + be1_s[e];
            sm.b.x1[e][t] = x1e;
            sm.b.zf[e][t] = cry_s[e] * __cosf(x1e);
        }
    }
    __syncthreads();

    // ---- P5: FFN, 256 threads, 4 rows/thread ----
    if (t < 256) {
        const int fs = t >> 5;
        const int rr = t & 31;
        f32x2 zf01[4], zf23[4], zf45[4], zf67[4];
        #pragma unroll
        for (int k = 0; k < 4; ++k) {
            const int row = rr + 32 * k;
            zf01[k] = (f32x2){sm.b.zf[0][row], sm.b.zf[1][row]};
            zf23[k] = (f32x2){sm.b.zf[2][row], sm.b.zf[3][row]};
            zf45[k] = (f32x2){sm.b.zf[4][row], sm.b.zf[5][row]};
            zf67[k] = (f32x2){sm.b.zf[6][row], sm.b.zf[7][row]};
        }
        f32x2 a01[4] = {}, a23[4] = {}, a45[4] = {}, a67[4] = {};
        #pragma unroll 4
        for (int i = 0; i < 64; ++i) {
            const int f = fs * 64 + i;
            const float4 wa = *reinterpret_cast<const float4*>(&w1_s[f][0]);
            const float4 wb = *reinterpret_cast<const float4*>(&w1_s[f][4]);
            const float bb = b1_s[f];
            const float4 ua = *reinterpret_cast<const float4*>(&w2t_s[f][0]);
            const float4 ub = *reinterpret_cast<const float4*>(&w2t_s[f][4]);
            const f32x2 wa01 = {wa.x, wa.y}, wa23 = {wa.z, wa.w};
            const f32x2 wb45 = {wb.x, wb.y}, wb67 = {wb.z, wb.w};
            const f32x2 ua01 = {ua.x, ua.y}, ua23 = {ua.z, ua.w};
            const f32x2 ub45 = {ub.x, ub.y}, ub67 = {ub.z, ub.w};
            #pragma unroll
            for (int k = 0; k < 4; ++k) {
                const f32x2 ha = zf01[k] * wa01 + zf23[k] * wa23;
                const f32x2 hb = zf45[k] * wb45 + zf67[k] * wb67;
                float hv = bb + ha.x + ha.y + hb.x + hb.y;
                hv = fmaxf(hv, 0.f);
                a01[k] += hv * ua01;  a23[k] += hv * ua23;
                a45[k] += hv * ub45;  a67[k] += hv * ub67;
            }
        }
        #pragma unroll
        for (int k = 0; k < 4; ++k) {
            const int row = rr + 32 * k;
            float* pf = &sm.b.part_f[fs][row][0];
            pf[0] = a01[k].x; pf[1] = a01[k].y; pf[2] = a23[k].x; pf[3] = a23[k].y;
            pf[4] = a45[k].x; pf[5] = a45[k].y; pf[6] = a67[k].x; pf[7] = a67[k].y;
        }
    }
    __syncthreads();

    // ---- P6a: reduce f-splits, add residual + b2 ----
    {
        const int e = t >> 7, r = t & 127;
        float s = 0.f;
        #pragma unroll
        for (int fs = 0; fs < 8; ++fs) s += sm.b.part_f[fs][r][e];
        sm.b.zf[e][r] = sm.b.x1[e][r] + s + b2_s[e];   // reuse zf as t2
    }
    __syncthreads();

    // ---- P6b: LN2 + store ----
    if (t < QPB) {
        float t2[NE];
        #pragma unroll
        for (int e = 0; e < NE; ++e) t2[e] = sm.b.zf[e][t];
        float mu = 0.f;
        #pragma unroll
        for (int e = 0; e < NE; ++e) mu += t2[e];
        mu *= 0.125f;
        float var = 0.f;
        #pragma unroll
        for (int e = 0; e < NE; ++e) { const float d = t2[e] - mu; var += d * d; }
        var *= 0.125f;
        const float inv2 = rsqrtf(var + LNEPS);
        float o[NE];
        #pragma unroll
        for (int e = 0; e < NE; ++e) o[e] = (t2[e] - mu) * inv2 * g2_s[e] + be2_s[e];
        float4* o4 = reinterpret_cast<float4*>(out + ((size_t)b * NS + qc * QPB + t) * NE);
        o4[0] = make_float4(o[0], o[1], o[2], o[3]);
        o4[1] = make_float4(o[4], o[5], o[6], o[7]);
    }
}

extern "C" void kernel_launch(void* const* d_in, const int* in_sizes, int n_in,
                              void* d_out, int out_size, void* d_ws, size_t ws_size,
                              hipStream_t stream) {
    const float* x        = (const float*)d_in[0];
    const float* theta_rx = (const float*)d_in[1];
    const float* w_out    = (const float*)d_in[2];
    const float* theta_ry = (const float*)d_in[3];
    const float* w1       = (const float*)d_in[4];
    const float* b1       = (const float*)d_in[5];
    const float* w2       = (const float*)d_in[6];
    const float* b2       = (const float*)d_in[7];
    const float* g1       = (const float*)d_in[8];
    const float* be1      = (const float*)d_in[9];
    const float* g2       = (const float*)d_in[10];
    const float* be2      = (const float*)d_in[11];
    float* out = (float*)d_out;
    float* ws  = (float*)d_ws;

    void* args[] = {&x, &theta_rx, &w_out, &theta_ry, &w1, &b1, &w2, &b2,
                    &g1, &be1, &g2, &be2, &ws, &out};
    hipLaunchCooperativeKernel((const void*)fused_qtb, dim3(NB * (NS / QPB)),
                               dim3(1024), args, 0, stream);
}

// Round 8
// 35.802 us; speedup vs baseline: 2.2707x; 2.2707x over previous
//
#include <hip/hip_runtime.h>
#include <math.h>
#include <utility>

#define NB 16
#define NS 2048
#define NE 8
#define NH 2
#define NF 512
#define DEG 6
#define NMONO 210          // #monomials in 4 vars, total degree <= 6
#define KPB 64             // keys per k1 block
#define NCHUNK 32          // key chunks per (b,h)
#define PHI_LD 66          // fp16 row stride (64 keys + 2 pad)
#define QPB 128
#define LNEPS 1e-5f
#define PART_STRIDE (5 * NMONO)

typedef float f32x2 __attribute__((ext_vector_type(2)));
typedef _Float16 h2 __attribute__((ext_vector_type(2)));

#if defined(__has_builtin)
# if __has_builtin(__builtin_amdgcn_fdot2)
#  define FDOT2(a,b,c) __builtin_amdgcn_fdot2((a),(b),(c),false)
# endif
#endif
#ifndef FDOT2
static __device__ __forceinline__ float fdot2_sw(h2 a, h2 b, float c) {
    return c + (float)a.x * (float)b.x + (float)a.y * (float)b.y;
}
# define FDOT2(a,b,c) fdot2_sw((a),(b),(c))
#endif

// Degree-6 truncated Chebyshev approx of e^x on [-2,2] in t=x/2 (power basis).
constexpr float ACOEF_C[7] = {0.99994459f, 2.00308514f, 2.00174650f,
                              1.30890404f, 0.65803033f, 0.31441604f, 0.10241921f};

constexpr int mono_e(int idx) {
    int i = 0;
    for (int e0 = 0; e0 <= DEG; ++e0)
        for (int e1 = 0; e1 <= DEG - e0; ++e1)
            for (int e2 = 0; e2 <= DEG - e0 - e1; ++e2)
                for (int e3 = 0; e3 <= DEG - e0 - e1 - e2; ++e3) {
                    if (i == idx) return (e0 << 12) | (e1 << 8) | (e2 << 4) | e3;
                    ++i;
                }
    return 0;
}
constexpr float mfact(int n) { float r = 1.f; for (int i = 2; i <= n; ++i) r *= (float)i; return r; }
constexpr float mono_c(int idx) {
    const int E = mono_e(idx);
    const int e0 = E >> 12, e1 = (E >> 8) & 15, e2 = (E >> 4) & 15, e3 = E & 15;
    const int d = e0 + e1 + e2 + e3;
    return ACOEF_C[d] * (mfact(d) / (mfact(e0) * mfact(e1) * mfact(e2) * mfact(e3)));
}

template <int BEG, class F, int... Is>
__device__ __forceinline__ void sf_impl(F f, std::integer_sequence<int, Is...>) {
    (f(std::integral_constant<int, BEG + Is>{}), ...);
}
template <int BEG, int END, class F>
__device__ __forceinline__ void static_for(F f) {
    sf_impl<BEG>(f, std::make_integer_sequence<int, END - BEG>{});
}

// ---------------- K1: per-64-key-chunk partial moments (r6, known-good) ----
template <int BEG, int END>
__device__ __forceinline__ void phi_body(_Float16* __restrict__ Phi, int lane,
                                         const float (&pw0)[7], const float (&pw1)[7],
                                         const float (&pw2)[7], const float (&pw3)[7]) {
    static_for<BEG, END>([&](auto Ic) {
        constexpr int idx = Ic.value;
        constexpr int E = mono_e(idx);
        constexpr float C = mono_c(idx);
        const float v = C * (pw0[E >> 12] * pw1[(E >> 8) & 15]) *
                            (pw2[(E >> 4) & 15] * pw3[E & 15]);
        Phi[idx * PHI_LD + lane] = (_Float16)v;
    });
}

__global__ __launch_bounds__(256, 4)
void k1_moments(const float* __restrict__ x, const float* __restrict__ theta_rx,
                float* __restrict__ ws) {
    __shared__ _Float16 Phi[NMONO * PHI_LD];          // 27.7 KB
    __shared__ __align__(16) _Float16 kvh[KPB / 2][8];
    __shared__ float th_s[8];

    const int t = threadIdx.x, bid = blockIdx.x;
    const int kc = bid & 31, h = (bid >> 5) & 1, b = bid >> 6;

    if (t < 8) th_s[t] = theta_rx[t];
    __syncthreads();

    const int lane = t & 63, wq = t >> 6;
    {
        const float* xr = x + ((size_t)b * NS + kc * KPB + lane) * NE;
        const float4 v0 = *reinterpret_cast<const float4*>(xr);
        const float4 v1 = *reinterpret_cast<const float4*>(xr + 4);
        const float c0 = __cosf(v0.x + th_s[0]), c1 = __cosf(v0.y + th_s[1]);
        const float c2 = __cosf(v0.z + th_s[2]), c3 = __cosf(v0.w + th_s[3]);
        const float c4 = __cosf(v1.x + th_s[4]), c5 = __cosf(v1.y + th_s[5]);
        const float c6 = __cosf(v1.z + th_s[6]), c7 = __cosf(v1.w + th_s[7]);
        const float p1 = c0*c1, p2 = p1*c2, p3 = p2*c3, p4 = p3*c4;
        const float p5 = p4*c5, p6 = p5*c6, p7 = p6*c7;
        float k0, k1v, k2v, k3v;
        if (h == 0) {
            const float s6 = c7*c6, s5 = s6*c5, s4 = s5*c4, s3 = s4*c3, s2 = s3*c2;
            k0 = s2*c1; k1v = p1; k2v = p2; k3v = p3;
        } else {
            k0 = p4; k1v = p5; k2v = p6; k3v = p7;
        }
        if (t < 64) {
            const int j = t >> 1, par = t & 1;
            kvh[j][0 + par] = (_Float16)k0;  kvh[j][2 + par] = (_Float16)k1v;
            kvh[j][4 + par] = (_Float16)k2v; kvh[j][6 + par] = (_Float16)k3v;
        }
        float pw0[7], pw1[7], pw2[7], pw3[7];
        pw0[0] = pw1[0] = pw2[0] = pw3[0] = 1.f;
        #pragma unroll
        for (int i = 1; i <= DEG; ++i) {
            pw0[i] = pw0[i-1] * k0;  pw1[i] = pw1[i-1] * k1v;
            pw2[i] = pw2[i-1] * k2v; pw3[i] = pw3[i-1] * k3v;
        }
        switch (wq) {   // wave-uniform: each wave builds its quarter of Phi
            case 0: phi_body<0,   53 >(Phi, lane, pw0, pw1, pw2, pw3); break;
            case 1: phi_body<53,  106>(Phi, lane, pw0, pw1, pw2, pw3); break;
            case 2: phi_body<106, 159>(Phi, lane, pw0, pw1, pw2, pw3); break;
            default: phi_body<159, 210>(Phi, lane, pw0, pw1, pw2, pw3); break;
        }
    }
    __syncthreads();

    if (t < NMONO) {
        const h2 one2 = {(_Float16)1.f, (_Float16)1.f};
        float a0 = 0.f, a1 = 0.f, a2 = 0.f, a3 = 0.f, a4 = 0.f;
        #pragma unroll 8
        for (int j = 0; j < KPB / 2; ++j) {
            const h2 phi2 = *reinterpret_cast<const h2*>(&Phi[t * PHI_LD + 2 * j]);
            const float4 kv4 = *reinterpret_cast<const float4*>(&kvh[j][0]);
            const h2 kA = __builtin_bit_cast(h2, kv4.x);
            const h2 kB = __builtin_bit_cast(h2, kv4.y);
            const h2 kC = __builtin_bit_cast(h2, kv4.z);
            const h2 kD = __builtin_bit_cast(h2, kv4.w);
            a0 = FDOT2(phi2, kA, a0);
            a1 = FDOT2(phi2, kB, a1);
            a2 = FDOT2(phi2, kC, a2);
            a3 = FDOT2(phi2, kD, a3);
            a4 = FDOT2(phi2, one2, a4);
        }
        float* dst = ws + (size_t)bid * PART_STRIDE;
        dst[0 * NMONO + t] = a0;
        dst[1 * NMONO + t] = a1;
        dst[2 * NMONO + t] = a2;
        dst[3 * NMONO + t] = a3;
        dst[4 * NMONO + t] = a4;
    }
}

// ---------------- K2: reduce + queries + fused epilogue ----------------
template <int BEG, int END>
__device__ __forceinline__ void p2_body2(const float4* __restrict__ Mn,
                                         const float* __restrict__ Md, int base,
                                         const float (&pwA)[4][7], const float (&pwB)[4][7],
                                         f32x2& a01A, f32x2& a23A, float& adA,
                                         f32x2& a01B, f32x2& a23B, float& adB) {
    static_for<BEG, END>([&](auto Ic) {
        constexpr int idx = Ic.value;
        constexpr int E = mono_e(idx);
        constexpr int e0 = E >> 12, e1 = (E >> 8) & 15, e2 = (E >> 4) & 15, e3 = E & 15;
        const float4 mv = Mn[base + idx];     // wave-uniform broadcast
        const float  md = Md[base + idx];
        const f32x2 m01 = {mv.x, mv.y}, m23 = {mv.z, mv.w};
        const float PA = (pwA[0][e0] * pwA[1][e1]) * (pwA[2][e2] * pwA[3][e3]);
        const float PB = (pwB[0][e0] * pwB[1][e1]) * (pwB[2][e2] * pwB[3][e3]);
        a01A += PA * m01;  a23A += PA * m23;  adA += PA * md;
        a01B += PB * m01;  a23B += PB * m23;  adB += PB * md;
    });
}

__global__ __launch_bounds__(1024)
void k2_main(const float* __restrict__ x, const float* __restrict__ theta_rx,
             const float* __restrict__ w_out, const float* __restrict__ theta_ry,
             const float* __restrict__ w1, const float* __restrict__ b1,
             const float* __restrict__ w2, const float* __restrict__ b2,
             const float* __restrict__ g1, const float* __restrict__ be1,
             const float* __restrict__ g2, const float* __restrict__ be2,
             const float* __restrict__ ws, float* __restrict__ out) {
    __shared__ float4 Mn_lds[2 * NMONO];
    __shared__ float  Md_lds[2 * NMONO];
    __shared__ float  z_c[8][QPB];
    __shared__ float  x1_c[8][QPB];
    __shared__ float  zf_c[8][QPB];            // later reused for t2
    __shared__ float  attn_c[8][QPB];
    __shared__ float  part_a[4][256][5];
    __shared__ float  part_f[8][QPB][9];       // [fsplit][row][e]; also reduce scratch
    __shared__ float  w1_s[NF][NE];
    __shared__ float  w2t_s[NF][NE];
    __shared__ float  b1_s[NF];
    __shared__ float  wout_s[NE][NE];
    __shared__ float  th_s[8], cry_s[8], g1_s[8], be1_s[8], g2_s[8], be2_s[8], b2_s[8];

    const int t = threadIdx.x, bid = blockIdx.x;
    const int b = bid >> 4, qc = bid & 15;

    float (*scr)[5] = (float(*)[5])&part_f[0][0][0];   // 840x5 scratch inside part_f

    // ---- R1: stage weights + partial PART reduce (16 chunks each) + z rows ----
    for (int i = t; i < NF * NE; i += 1024) {
        ((float*)w1_s)[i] = w1[i];
        const int e = i >> 9, f = i & (NF - 1);
        w2t_s[f][e] = w2[i];
    }
    if (t < NF) b1_s[t] = b1[t];
    if (t < NE * NE) ((float*)wout_s)[t] = w_out[t];
    if (t < 8) {
        th_s[t]  = theta_rx[t];
        cry_s[t] = __cosf(theta_ry[t]);
        g1_s[t]  = g1[t];  be1_s[t] = be1[t];
        g2_s[t]  = g2[t];  be2_s[t] = be2[t];
        b2_s[t]  = b2[t];
    }
    if (t < 840) {                      // partial reduce: (half, h, a)
        const int half = t / 420;
        const int a2 = t - half * 420;
        const int h = (a2 >= NMONO) ? 1 : 0;
        const int a = a2 - h * NMONO;
        const float* src = ws + (size_t)((b * 2 + h) * NCHUNK + half * 16) * PART_STRIDE;
        float s0 = 0.f, s1 = 0.f, s2 = 0.f, s3 = 0.f, s4 = 0.f;
        #pragma unroll 4
        for (int kc = 0; kc < 16; ++kc) {
            const float* p = src + (size_t)kc * PART_STRIDE;
            s0 += p[0 * NMONO + a]; s1 += p[1 * NMONO + a];
            s2 += p[2 * NMONO + a]; s3 += p[3 * NMONO + a];
            s4 += p[4 * NMONO + a];
        }
        float* d = scr[t];
        d[0] = s0; d[1] = s1; d[2] = s2; d[3] = s3; d[4] = s4;
    }
    if (t >= 896) {                     // z for the 128 query rows (theta from global)
        const int r = t - 896;
        const float* xr = x + ((size_t)b * NS + qc * QPB + r) * NE;
        const float4 v0 = *reinterpret_cast<const float4*>(xr);
        const float4 v1 = *reinterpret_cast<const float4*>(xr + 4);
        const float4 ta = *reinterpret_cast<const float4*>(theta_rx);
        const float4 tb = *reinterpret_cast<const float4*>(theta_rx + 4);
        const float c0 = __cosf(v0.x + ta.x), c1 = __cosf(v0.y + ta.y);
        const float c2 = __cosf(v0.z + ta.z), c3 = __cosf(v0.w + ta.w);
        const float c4 = __cosf(v1.x + tb.x), c5 = __cosf(v1.y + tb.y);
        const float c6 = __cosf(v1.z + tb.z), c7 = __cosf(v1.w + tb.w);
        const float p1 = c0*c1, p2 = p1*c2, p3 = p2*c3, p4 = p3*c4;
        const float p5 = p4*c5, p6 = p5*c6, p7 = p6*c7;
        const float s6 = c7*c6, s5 = s6*c5, s4 = s5*c4, s3 = s4*c3, s2 = s3*c2;
        z_c[0][r] = s2*c1; z_c[1][r] = p1; z_c[2][r] = p2; z_c[3][r] = p3;
        z_c[4][r] = p4;    z_c[5][r] = p5; z_c[6][r] = p6; z_c[7][r] = p7;
    }
    __syncthreads();

    // ---- R2: combine the two 16-chunk halves -> moments ----
    if (t < 2 * NMONO) {
        const float* pa = scr[t];
        const float* pb = scr[t + 420];
        Mn_lds[t] = make_float4(pa[0] + pb[0], pa[1] + pb[1],
                                pa[2] + pb[2], pa[3] + pb[3]);
        Md_lds[t] = pa[4] + pb[4];
    }
    __syncthreads();

    // ---- P2: 8 waves, wave = (g,h), 2 rows per lane ----
    if (t < 512) {
        const int w = t >> 6, l = t & 63;
        const int g = w >> 1, h = w & 1;
        const int rA = l, rB = l + 64;
        float pwA[4][7], pwB[4][7];
        #pragma unroll
        for (int d = 0; d < 4; ++d) {
            const float uA = z_c[h*4+d][rA] * 0.25f;
            const float uB = z_c[h*4+d][rB] * 0.25f;
            pwA[d][0] = 1.f; pwB[d][0] = 1.f;
            #pragma unroll
            for (int i = 1; i <= DEG; ++i) {
                pwA[d][i] = pwA[d][i-1] * uA;
                pwB[d][i] = pwB[d][i-1] * uB;
            }
        }
        f32x2 a01A = {0.f,0.f}, a23A = {0.f,0.f}, a01B = {0.f,0.f}, a23B = {0.f,0.f};
        float adA = 0.f, adB = 0.f;
        const int base = h * NMONO;
        switch (g) {
            case 0: p2_body2<0,   53 >(Mn_lds, Md_lds, base, pwA, pwB, a01A, a23A, adA, a01B, a23B, adB); break;
            case 1: p2_body2<53,  106>(Mn_lds, Md_lds, base, pwA, pwB, a01A, a23A, adA, a01B, a23B, adB); break;
            case 2: p2_body2<106, 159>(Mn_lds, Md_lds, base, pwA, pwB, a01A, a23A, adA, a01B, a23B, adB); break;
            default: p2_body2<159, 210>(Mn_lds, Md_lds, base, pwA, pwB, a01A, a23A, adA, a01B, a23B, adB); break;
        }
        float* pa = &part_a[g][h * 128 + rA][0];
        pa[0] = a01A.x; pa[1] = a01A.y; pa[2] = a23A.x; pa[3] = a23A.y; pa[4] = adA;
        float* pb = &part_a[g][h * 128 + rB][0];
        pb[0] = a01B.x; pb[1] = a01B.y; pb[2] = a23B.x; pb[3] = a23B.y; pb[4] = adB;
    }
    __syncthreads();

    // ---- P3: combine groups, normalize ----
    if (t < 256) {
        const int h = t >> 7, r = t & 127;
        float n0 = 0.f, n1 = 0.f, n2 = 0.f, n3 = 0.f, dd = 0.f;
        #pragma unroll
        for (int g = 0; g < 4; ++g) {
            const float* pa = &part_a[g][t][0];
            n0 += pa[0]; n1 += pa[1]; n2 += pa[2]; n3 += pa[3]; dd += pa[4];
        }
        const float inv = 1.0f / dd;
        attn_c[h*4+0][r] = n0 * inv; attn_c[h*4+1][r] = n1 * inv;
        attn_c[h*4+2][r] = n2 * inv; attn_c[h*4+3][r] = n3 * inv;
    }
    __syncthreads();

    // ---- P4: out_proj -> LN1 -> zf ----
    if (t < QPB) {
        float av[NE];
        #pragma unroll
        for (int e = 0; e < NE; ++e) av[e] = attn_c[e][t];
        float y[NE];
        #pragma unroll
        for (int e = 0; e < NE; ++e) {
            float acc = 0.f;
            #pragma unroll
            for (int k = 0; k < NE; ++k) acc += av[k] * wout_s[e][k];
            y[e] = acc;
        }
        const float* xr = x + ((size_t)b * NS + qc * QPB + t) * NE;
        const float4 xv0 = *reinterpret_cast<const float4*>(xr);
        const float4 xv1 = *reinterpret_cast<const float4*>(xr + 4);
        float t1[NE];
        t1[0] = xv0.x + y[0]; t1[1] = xv0.y + y[1]; t1[2] = xv0.z + y[2]; t1[3] = xv0.w + y[3];
        t1[4] = xv1.x + y[4]; t1[5] = xv1.y + y[5]; t1[6] = xv1.z + y[6]; t1[7] = xv1.w + y[7];
        float mu = 0.f;
        #pragma unroll
        for (int e = 0; e < NE; ++e) mu += t1[e];
        mu *= 0.125f;
        float var = 0.f;
        #pragma unroll
        for (int e = 0; e < NE; ++e) { const float d = t1[e] - mu; var += d * d; }
        var *= 0.125f;
        const float inv1 = rsqrtf(var + LNEPS);
        #pragma unroll
        for (int e = 0; e < NE; ++e) {
            const float x1e = (t1[e] - mu) * inv1 * g1_s[e] + be1_s[e];
            x1_c[e][t] = x1e;
            zf_c[e][t] = cry_s[e] * __cosf(x1e);
        }
    }
    __syncthreads();

    // ---- P5: FFN, 256 threads, 4 rows/thread ----
    if (t < 256) {
        const int fs = t >> 5;
        const int rr = t & 31;
        f32x2 zf01[4], zf23[4], zf45[4], zf67[4];
        #pragma unroll
        for (int k = 0; k < 4; ++k) {
            const int row = rr + 32 * k;
            zf01[k] = (f32x2){zf_c[0][row], zf_c[1][row]};
            zf23[k] = (f32x2){zf_c[2][row], zf_c[3][row]};
            zf45[k] = (f32x2){zf_c[4][row], zf_c[5][row]};
            zf67[k] = (f32x2){zf_c[6][row], zf_c[7][row]};
        }
        f32x2 a01[4] = {}, a23[4] = {}, a45[4] = {}, a67[4] = {};
        #pragma unroll 4
        for (int i = 0; i < 64; ++i) {
            const int f = fs * 64 + i;
            const float4 wa = *reinterpret_cast<const float4*>(&w1_s[f][0]);
            const float4 wb = *reinterpret_cast<const float4*>(&w1_s[f][4]);
            const float bb = b1_s[f];
            const float4 ua = *reinterpret_cast<const float4*>(&w2t_s[f][0]);
            const float4 ub = *reinterpret_cast<const float4*>(&w2t_s[f][4]);
            const f32x2 wa01 = {wa.x, wa.y}, wa23 = {wa.z, wa.w};
            const f32x2 wb45 = {wb.x, wb.y}, wb67 = {wb.z, wb.w};
            const f32x2 ua01 = {ua.x, ua.y}, ua23 = {ua.z, ua.w};
            const f32x2 ub45 = {ub.x, ub.y}, ub67 = {ub.z, ub.w};
            #pragma unroll
            for (int k = 0; k < 4; ++k) {
                const f32x2 ha = zf01[k] * wa01 + zf23[k] * wa23;
                const f32x2 hb = zf45[k] * wb45 + zf67[k] * wb67;
                float hv = bb + ha.x + ha.y + hb.x + hb.y;
                hv = fmaxf(hv, 0.f);
                a01[k] += hv * ua01;  a23[k] += hv * ua23;
                a45[k] += hv * ub45;  a67[k] += hv * ub67;
            }
        }
        #pragma unroll
        for (int k = 0; k < 4; ++k) {
            const int row = rr + 32 * k;
            float* pf = &part_f[fs][row][0];
            pf[0] = a01[k].x; pf[1] = a01[k].y; pf[2] = a23[k].x; pf[3] = a23[k].y;
            pf[4] = a45[k].x; pf[5] = a45[k].y; pf[6] = a67[k].x; pf[7] = a67[k].y;
        }
    }
    __syncthreads();

    // ---- P6a: reduce f-splits, add residual + b2 ----
    {
        const int e = t >> 7, r = t & 127;
        float s = 0.f;
        #pragma unroll
        for (int fs = 0; fs < 8; ++fs) s += part_f[fs][r][e];
        zf_c[e][r] = x1_c[e][r] + s + b2_s[e];   // reuse zf_c as t2
    }
    __syncthreads();

    // ---- P6b: LN2 + store ----
    if (t < QPB) {
        float t2[NE];
        #pragma unroll
        for (int e = 0; e < NE; ++e) t2[e] = zf_c[e][t];
        float mu = 0.f;
        #pragma unroll
        for (int e = 0; e < NE; ++e) mu += t2[e];
        mu *= 0.125f;
        float var = 0.f;
        #pragma unroll
        for (int e = 0; e < NE; ++e) { const float d = t2[e] - mu; var += d * d; }
        var *= 0.125f;
        const float inv2 = rsqrtf(var + LNEPS);
        float o[NE];
        #pragma unroll
        for (int e = 0; e < NE; ++e) o[e] = (t2[e] - mu) * inv2 * g2_s[e] + be2_s[e];
        float4* o4 = reinterpret_cast<float4*>(out + ((size_t)b * NS + qc * QPB + t) * NE);
        o4[0] = make_float4(o[0], o[1], o[2], o[3]);
        o4[1] = make_float4(o[4], o[5], o[6], o[7]);
    }
}

extern "C" void kernel_launch(void* const* d_in, const int* in_sizes, int n_in,
                              void* d_out, int out_size, void* d_ws, size_t ws_size,
                              hipStream_t stream) {
    const float* x        = (const float*)d_in[0];
    const float* theta_rx = (const float*)d_in[1];
    const float* w_out    = (const float*)d_in[2];
    const float* theta_ry = (const float*)d_in[3];
    const float* w1       = (const float*)d_in[4];
    const float* b1       = (const float*)d_in[5];
    const float* w2       = (const float*)d_in[6];
    const float* b2       = (const float*)d_in[7];
    const float* g1       = (const float*)d_in[8];
    const float* be1      = (const float*)d_in[9];
    const float* g2       = (const float*)d_in[10];
    const float* be2      = (const float*)d_in[11];
    float* out = (float*)d_out;
    float* ws  = (float*)d_ws;

    k1_moments<<<dim3(NB * NH * NCHUNK), dim3(256), 0, stream>>>(x, theta_rx, ws);
    k2_main<<<dim3(NB * (NS / QPB)), dim3(1024), 0, stream>>>(
        x, theta_rx, w_out, theta_ry, w1, b1, w2, b2, g1, be1, g2, be2, ws, out);
}